// Round 4
// baseline (3438.285 us; speedup 1.0000x reference)
//
#include <hip/hip_runtime.h>
#include <math.h>

#define NFEAT 512
#define NHID  256
#define NCLS  64
#define KHOP  10
#define LDSTRIDE 56   // bf16 elems; 112B rows -> 16B aligned, 2-way bank alias (free)
#define DEGPAD 16     // pad each node's degree to multiple of 16 (prop unroll)

typedef __attribute__((ext_vector_type(8))) short short8;
typedef __attribute__((ext_vector_type(4))) float f32x4;

__device__ __forceinline__ unsigned short f2bf(float f) {
    unsigned u = __float_as_uint(f);
    u += 0x7FFFu + ((u >> 16) & 1u);       // RNE
    return (unsigned short)(u >> 16);
}
__device__ __forceinline__ float bf2f(unsigned short h) {
    return __uint_as_float((unsigned)h << 16);
}
__device__ __forceinline__ float bflo(unsigned w) { return __uint_as_float(w << 16); }
__device__ __forceinline__ float bfhi(unsigned w) { return __uint_as_float(w & 0xFFFF0000u); }

// ---------------- casts ----------------
__global__ __launch_bounds__(256) void cast_kernel(const float* __restrict__ src,
                                                   unsigned short* __restrict__ dst, long n)
{
    long i = (long)blockIdx.x * 1024 + (long)threadIdx.x * 4;
    if (i + 3 < n) {
        float4 v = *(const float4*)(src + i);
        dst[i+0] = f2bf(v.x); dst[i+1] = f2bf(v.y);
        dst[i+2] = f2bf(v.z); dst[i+3] = f2bf(v.w);
    } else {
        for (int j = 0; j < 4 && i + j < n; j++) dst[i+j] = f2bf(src[i+j]);
    }
}

__global__ __launch_bounds__(256) void castT_kernel(const float* __restrict__ src,
                                                    unsigned short* __restrict__ dst,
                                                    int K, int N)
{
    int i = blockIdx.x * 256 + threadIdx.x;
    if (i < K * N) {
        int k = i / N, n = i % N;
        dst[(long)n * K + k] = f2bf(src[i]);
    }
}

// ---------------- MFMA GEMM1: hmid = relu(x @ W1 + b1) ----------------------
__global__ __launch_bounds__(256) void mfma_gemm1(
    const unsigned short* __restrict__ A, const unsigned short* __restrict__ BT,
    const float* __restrict__ bias, unsigned short* __restrict__ C, int M)
{
    __shared__ unsigned short As[128 * LDSTRIDE];
    __shared__ unsigned short Bs[128 * LDSTRIDE];
    const int tid = threadIdx.x;
    const int wave = tid >> 6, lane = tid & 63;
    const int quad = lane >> 4, l16 = lane & 15;
    const int wm = wave >> 1, wn = wave & 1;
    const int m0 = blockIdx.x * 128, n0 = blockIdx.y * 128;

    f32x4 acc[4][4] = {};
    const int srow = tid >> 2;
    const int schunk = (tid & 3) * 8;

    for (int k0 = 0; k0 < NFEAT; k0 += 32) {
        #pragma unroll
        for (int i = 0; i < 2; i++) {
            int r = srow + i * 64;
            int rg = m0 + r;
            short8 v = {};
            if (rg < M) v = *(const short8*)(A + (long)rg * NFEAT + k0 + schunk);
            *(short8*)(As + r * LDSTRIDE + schunk) = v;
        }
        #pragma unroll
        for (int i = 0; i < 2; i++) {
            int r = srow + i * 64;
            short8 v = *(const short8*)(BT + (long)(n0 + r) * NFEAT + k0 + schunk);
            *(short8*)(Bs + r * LDSTRIDE + schunk) = v;
        }
        __syncthreads();
        short8 af[4], bfr[4];
        #pragma unroll
        for (int mi = 0; mi < 4; mi++)
            af[mi] = *(const short8*)(As + (wm*64 + mi*16 + l16) * LDSTRIDE + quad*8);
        #pragma unroll
        for (int nj = 0; nj < 4; nj++)
            bfr[nj] = *(const short8*)(Bs + (wn*64 + nj*16 + l16) * LDSTRIDE + quad*8);
        #pragma unroll
        for (int mi = 0; mi < 4; mi++)
            #pragma unroll
            for (int nj = 0; nj < 4; nj++)
                acc[mi][nj] = __builtin_amdgcn_mfma_f32_16x16x32_bf16(af[mi], bfr[nj], acc[mi][nj], 0, 0, 0);
        __syncthreads();
    }

    #pragma unroll
    for (int mi = 0; mi < 4; mi++)
        #pragma unroll
        for (int r = 0; r < 4; r++) {
            int row = m0 + wm*64 + mi*16 + quad*4 + r;
            if (row >= M) continue;
            #pragma unroll
            for (int nj = 0; nj < 4; nj++) {
                int col = n0 + wn*64 + nj*16 + l16;
                float v = acc[mi][nj][r] + bias[col];
                C[(long)row * NHID + col] = f2bf(fmaxf(v, 0.f));
            }
        }
}

// ------- MFMA GEMM2: v = hmid@W2 + b2; s0 = bf16(dis*v); hidden = temp0*v ----
__global__ __launch_bounds__(256) void mfma_gemm2(
    const unsigned short* __restrict__ A, const unsigned short* __restrict__ BT,
    const float* __restrict__ bias, unsigned short* __restrict__ S,
    float* __restrict__ hidden, const float* __restrict__ temp,
    const float* __restrict__ dis, int M)
{
    __shared__ unsigned short As[128 * LDSTRIDE];
    __shared__ unsigned short Bs[64 * LDSTRIDE];
    const int tid = threadIdx.x;
    const int wave = tid >> 6, lane = tid & 63;
    const int quad = lane >> 4, l16 = lane & 15;
    const int m0 = blockIdx.x * 128;
    const float t0 = temp[0];

    f32x4 acc[2][4] = {};
    const int srow = tid >> 2;
    const int schunk = (tid & 3) * 8;

    for (int k0 = 0; k0 < NHID; k0 += 32) {
        #pragma unroll
        for (int i = 0; i < 2; i++) {
            int r = srow + i * 64;
            int rg = m0 + r;
            short8 v = {};
            if (rg < M) v = *(const short8*)(A + (long)rg * NHID + k0 + schunk);
            *(short8*)(As + r * LDSTRIDE + schunk) = v;
        }
        {
            short8 v = *(const short8*)(BT + (long)srow * NHID + k0 + schunk);
            *(short8*)(Bs + srow * LDSTRIDE + schunk) = v;
        }
        __syncthreads();
        short8 af[2], bfr[4];
        #pragma unroll
        for (int mi = 0; mi < 2; mi++)
            af[mi] = *(const short8*)(As + (wave*32 + mi*16 + l16) * LDSTRIDE + quad*8);
        #pragma unroll
        for (int nj = 0; nj < 4; nj++)
            bfr[nj] = *(const short8*)(Bs + (nj*16 + l16) * LDSTRIDE + quad*8);
        #pragma unroll
        for (int mi = 0; mi < 2; mi++)
            #pragma unroll
            for (int nj = 0; nj < 4; nj++)
                acc[mi][nj] = __builtin_amdgcn_mfma_f32_16x16x32_bf16(af[mi], bfr[nj], acc[mi][nj], 0, 0, 0);
        __syncthreads();
    }

    #pragma unroll
    for (int mi = 0; mi < 2; mi++)
        #pragma unroll
        for (int r = 0; r < 4; r++) {
            int row = m0 + wave*32 + mi*16 + quad*4 + r;
            if (row >= M) continue;
            float dr = dis[row];
            #pragma unroll
            for (int nj = 0; nj < 4; nj++) {
                int col = nj*16 + l16;
                float v = acc[mi][nj][r] + bias[col];
                long idx = (long)row * NCLS + col;
                S[idx] = f2bf(dr * v);
                hidden[idx] = t0 * v;
            }
        }
}

// ---------------- graph preprocessing ----------------
// pass A: per-node in-degree + per-bucket edge count
__global__ void countA_kernel(const int* __restrict__ ei, int E,
                              int* __restrict__ cnt, int* __restrict__ bcnt)
{
    int e = blockIdx.x * blockDim.x + threadIdx.x;
    if (e >= E) return;
    int c = ei[E + e];
    atomicAdd(&cnt[c], 1);
    atomicAdd(&bcnt[c >> 8], 1);
}

__global__ void dis_kernel(const int* __restrict__ cnt, float* __restrict__ dis, int Nn)
{
    int v = blockIdx.x * blockDim.x + threadIdx.x;
    if (v < Nn) dis[v] = rsqrtf((float)(cnt[v] + 1));
}

// block sums of padded counts
__global__ __launch_bounds__(256) void bsum_kernel(const int* __restrict__ cnt, int n,
                                                   int* __restrict__ bsum)
{
    __shared__ int ws[4];
    int i = blockIdx.x * 256 + threadIdx.x;
    int v = (i < n) ? ((cnt[i] + DEGPAD - 1) & ~(DEGPAD - 1)) : 0;
    #pragma unroll
    for (int off = 1; off < 64; off <<= 1) v += __shfl_xor(v, off);
    if ((threadIdx.x & 63) == 0) ws[threadIdx.x >> 6] = v;
    __syncthreads();
    if (threadIdx.x == 0) bsum[blockIdx.x] = ws[0] + ws[1] + ws[2] + ws[3];
}

__global__ __launch_bounds__(512) void bscan_kernel(int* __restrict__ bsum, int nb)
{
    __shared__ int buf[512];
    int i = threadIdx.x;
    int v = (i < nb) ? bsum[i] : 0;
    buf[i] = v;
    __syncthreads();
    for (int off = 1; off < 512; off <<= 1) {
        int t = (i >= off) ? buf[i - off] : 0;
        __syncthreads();
        buf[i] += t;
        __syncthreads();
    }
    if (i < nb) bsum[i] = buf[i] - v;   // exclusive
}

// exclusive scan of bucket counts -> boff[0..nb], boff[nb]=total
__global__ __launch_bounds__(512) void bscan2_kernel(const int* __restrict__ bcnt,
                                                     int* __restrict__ boff, int nb)
{
    __shared__ int buf[512];
    int i = threadIdx.x;
    int v = (i < nb) ? bcnt[i] : 0;
    buf[i] = v;
    __syncthreads();
    for (int off = 1; off < 512; off <<= 1) {
        int t = (i >= off) ? buf[i - off] : 0;
        __syncthreads();
        buf[i] += t;
        __syncthreads();
    }
    if (i < nb) boff[i] = buf[i] - v;
    if (i == nb - 1) boff[nb] = buf[i];
}

__global__ __launch_bounds__(256) void pscan_kernel(const int* __restrict__ cnt, int n,
                                                    const int* __restrict__ bsum,
                                                    int* __restrict__ ptr)
{
    __shared__ int buf[256];
    int i = blockIdx.x * 256 + threadIdx.x;
    int v = (i < n) ? ((cnt[i] + DEGPAD - 1) & ~(DEGPAD - 1)) : 0;
    buf[threadIdx.x] = v;
    __syncthreads();
    for (int off = 1; off < 256; off <<= 1) {
        int t = (threadIdx.x >= off) ? buf[threadIdx.x - off] : 0;
        __syncthreads();
        buf[threadIdx.x] += t;
        __syncthreads();
    }
    if (i < n) ptr[i] = bsum[blockIdx.x] + buf[threadIdx.x] - v;
    if (i == n - 1) ptr[n] = bsum[blockIdx.x] + buf[threadIdx.x];
}

// pass B: scatter-append (r,c) into destination buckets (write-local tails)
__global__ void bucket_scatter(const int* __restrict__ ei, int E,
                               const int* __restrict__ boff, int* __restrict__ btail,
                               int2* __restrict__ ebuf)
{
    int e = blockIdx.x * blockDim.x + threadIdx.x;
    if (e >= E) return;
    int r = ei[e];
    int c = ei[E + e];
    int b = c >> 8;
    int pos = atomicAdd(&btail[b], 1);
    ebuf[boff[b] + pos] = make_int2(r, c);
}

// pass C: per-bucket CSR fill (adj writes localized to a ~32KB window)
__global__ __launch_bounds__(256) void csr_fill(const int2* __restrict__ ebuf,
                                                const int* __restrict__ boff,
                                                const int* __restrict__ ptr,
                                                int* __restrict__ fill,
                                                int* __restrict__ adj)
{
    int b = blockIdx.x;
    int s = boff[b], t = boff[b + 1];
    for (int i = s + blockIdx.y * 256 + threadIdx.x; i < t; i += gridDim.y * 256) {
        int2 rc = ebuf[i];
        int pos = atomicAdd(&fill[rc.y], 1);
        adj[ptr[rc.y] + pos] = rc.x;
    }
}

__global__ void padfill_kernel(const int* __restrict__ cnt, const int* __restrict__ ptr,
                               int* __restrict__ adj, int Nn)
{
    int v = blockIdx.x * 256 + threadIdx.x;
    if (v >= Nn) return;
    int b = ptr[v] + cnt[v], e = ptr[v + 1];
    for (int i = b; i < e; i++) adj[i] = Nn;
}

__global__ void zdum_kernel(unsigned short* __restrict__ sA,
                            unsigned short* __restrict__ sB, int Nn)
{
    int i = threadIdx.x;
    if (i < 64) sA[(long)Nn * NCLS + i] = 0;
    else        sB[(long)Nn * NCLS + (i - 64)] = 0;
}

// -------- K-hop propagation: 1 wave/node, 2 classes/lane, 16 edges/iter -----
// s_{k+1}[v] = d_v^2 (s_k[v] + sum_{u in N(v)} s_k[u]); hidden += temp*d_v*(...)
__global__ __launch_bounds__(256) void prop_kernel(
    const unsigned short* __restrict__ sin, unsigned short* __restrict__ sout,
    float* __restrict__ hidden,
    const int* __restrict__ ptr, const int* __restrict__ adj,
    const float* __restrict__ dis, const float* __restrict__ temp, int k, int Nn)
{
    const int wave = threadIdx.x >> 6, lane = threadIdx.x & 63;
    const int v = blockIdx.x * 4 + wave;
    if (v >= Nn) return;

    const int half = lane >> 5;          // 0: even neighbors, 1: odd group
    const int col2 = lane & 31;          // which class-pair
    const unsigned* __restrict__ s32 = (const unsigned*)sin;

    const int beg = ptr[v], end = ptr[v + 1];
    const float d = dis[v];

    float ax = 0.f, ay = 0.f;
    {   // self-loop term: add only in lower half (avoid double count after fold)
        unsigned w = s32[(long)v * 32 + col2];
        if (half == 0) { ax = bflo(w); ay = bfhi(w); }
    }

    for (int e = beg; e < end; e += 16) {
        int base = e + (half << 3);
        int4 u0 = *(const int4*)(adj + base);
        int4 u1 = *(const int4*)(adj + base + 4);
        unsigned w0 = s32[(long)u0.x * 32 + col2];
        unsigned w1 = s32[(long)u0.y * 32 + col2];
        unsigned w2 = s32[(long)u0.z * 32 + col2];
        unsigned w3 = s32[(long)u0.w * 32 + col2];
        unsigned w4 = s32[(long)u1.x * 32 + col2];
        unsigned w5 = s32[(long)u1.y * 32 + col2];
        unsigned w6 = s32[(long)u1.z * 32 + col2];
        unsigned w7 = s32[(long)u1.w * 32 + col2];
        ax += ((bflo(w0) + bflo(w1)) + (bflo(w2) + bflo(w3)))
            + ((bflo(w4) + bflo(w5)) + (bflo(w6) + bflo(w7)));
        ay += ((bfhi(w0) + bfhi(w1)) + (bfhi(w2) + bfhi(w3)))
            + ((bfhi(w4) + bfhi(w5)) + (bfhi(w6) + bfhi(w7)));
    }

    // fold upper half into lower
    ax += __shfl_xor(ax, 32);
    ay += __shfl_xor(ay, 32);

    if (half == 0) {
        int col = col2 * 2;
        long idx = (long)v * NCLS + col;
        float h0 = d * ax, h1 = d * ay;
        float tk = temp[k + 1];
        float2* hp = (float2*)(hidden + idx);
        float2 hv = *hp;
        hv.x += tk * h0; hv.y += tk * h1;
        *hp = hv;
        unsigned pack = (unsigned)f2bf(d * h0) | ((unsigned)f2bf(d * h1) << 16);
        *(unsigned*)(sout + idx) = pack;
    }
}

// ---------------- log-softmax ----------------
__global__ __launch_bounds__(256) void lsm_kernel(const float* __restrict__ hidden,
                                                  float* __restrict__ out, int Nn)
{
    const int wave = threadIdx.x >> 6, lane = threadIdx.x & 63;
    const int v = blockIdx.x * 4 + wave;
    if (v >= Nn) return;
    float x = hidden[(long)v * NCLS + lane];
    float m = x;
    #pragma unroll
    for (int off = 32; off > 0; off >>= 1) m = fmaxf(m, __shfl_xor(m, off));
    float s = __expf(x - m);
    #pragma unroll
    for (int off = 32; off > 0; off >>= 1) s += __shfl_xor(s, off);
    out[(long)v * NCLS + lane] = x - m - logf(s);
}

// ---------------- launcher ----------------
extern "C" void kernel_launch(void* const* d_in, const int* in_sizes, int n_in,
                              void* d_out, int out_size, void* d_ws, size_t ws_size,
                              hipStream_t stream)
{
    const float* x    = (const float*)d_in[0];
    const int*   ei   = (const int*)  d_in[1];
    const float* W1   = (const float*)d_in[2];
    const float* b1   = (const float*)d_in[3];
    const float* W2   = (const float*)d_in[4];
    const float* b2   = (const float*)d_in[5];
    const float* temp = (const float*)d_in[6];

    const int Nn = in_sizes[0] / NFEAT;   // 100000
    const int E  = in_sizes[1] / 2;       // 3200000
    const int nbk = ((Nn - 1) >> 8) + 1;  // 391 buckets of 256 nodes

    char* ws = (char*)d_ws;
    size_t off = 0;
    auto alloc = [&](size_t bytes) { size_t o = off; off += (bytes + 255) & ~255ull; return o; };

    // region0: x_bf (102.4 MB); reused after GEMM1 for adj|sA|sB|hidden|ebuf (96 MB)
    size_t r0 = alloc((size_t)Nn * NFEAT * 2);
    size_t hmid_off = alloc((size_t)Nn * NHID * 2);
    size_t w1t_off  = alloc((size_t)NFEAT * NHID * 2);
    size_t w2t_off  = alloc((size_t)NHID * NCLS * 2);
    size_t cnt_off  = alloc((size_t)Nn * 4);
    size_t fill_off = alloc((size_t)Nn * 4);
    size_t dis_off  = alloc((size_t)Nn * 4);
    size_t ptr_off  = alloc((size_t)(Nn + 1) * 4);
    size_t bsum_off = alloc(((size_t)Nn / 256 + 2) * 4);
    size_t bcnt_off = alloc((size_t)(nbk + 1) * 4);
    size_t boff_off = alloc((size_t)(nbk + 1) * 4);
    size_t btail_off= alloc((size_t)(nbk + 1) * 4);

    unsigned short* x_bf = (unsigned short*)(ws + r0);
    unsigned short* hmid = (unsigned short*)(ws + hmid_off);
    unsigned short* W1T  = (unsigned short*)(ws + w1t_off);
    unsigned short* W2T  = (unsigned short*)(ws + w2t_off);
    int*   cnt   = (int*)  (ws + cnt_off);
    int*   fillb = (int*)  (ws + fill_off);
    float* dis   = (float*)(ws + dis_off);
    int*   ptr   = (int*)  (ws + ptr_off);
    int*   bsum  = (int*)  (ws + bsum_off);
    int*   bcnt  = (int*)  (ws + bcnt_off);
    int*   boff  = (int*)  (ws + boff_off);
    int*   btail = (int*)  (ws + btail_off);

    // region0 reuse
    size_t Epad  = (size_t)E + (size_t)DEGPAD * Nn;         // 4.8M ints
    size_t adjB  = Epad * 4;                                 // 19.2 MB
    size_t sBsz  = (size_t)(Nn + 1) * NCLS * 2;              // 12.8 MB
    size_t hidB  = (size_t)Nn * NCLS * 4;                    // 25.6 MB
    int*            adj    = (int*)           (ws + r0);
    unsigned short* sA     = (unsigned short*)(ws + r0 + adjB);
    unsigned short* sB     = (unsigned short*)(ws + r0 + adjB + sBsz);
    float*          hidden = (float*)         (ws + r0 + adjB + 2 * sBsz);
    int2*           ebuf   = (int2*)          (ws + r0 + adjB + 2 * sBsz + hidB);

    // ---- casts ----
    cast_kernel<<<(int)(((long)Nn * NFEAT + 1023) / 1024), 256, 0, stream>>>(x, x_bf, (long)Nn * NFEAT);
    castT_kernel<<<(NFEAT * NHID + 255) / 256, 256, 0, stream>>>(W1, W1T, NFEAT, NHID);
    castT_kernel<<<(NHID * NCLS + 255) / 256, 256, 0, stream>>>(W2, W2T, NHID, NCLS);

    // ---- GEMM1 (consumes x_bf) ----
    {
        dim3 g((Nn + 127) / 128, NHID / 128);
        mfma_gemm1<<<g, 256, 0, stream>>>(x_bf, W1T, b1, hmid, Nn);
    }

    // ---- CSR build (x_bf region now dead) ----
    hipMemsetAsync(cnt,   0, (size_t)Nn * 4, stream);
    hipMemsetAsync(fillb, 0, (size_t)Nn * 4, stream);
    hipMemsetAsync(bcnt,  0, (size_t)(nbk + 1) * 4, stream);
    hipMemsetAsync(btail, 0, (size_t)(nbk + 1) * 4, stream);
    countA_kernel<<<(E + 255) / 256, 256, 0, stream>>>(ei, E, cnt, bcnt);
    dis_kernel<<<(Nn + 255) / 256, 256, 0, stream>>>(cnt, dis, Nn);
    int nb = (Nn + 255) / 256;
    bsum_kernel<<<nb, 256, 0, stream>>>(cnt, Nn, bsum);
    bscan_kernel<<<1, 512, 0, stream>>>(bsum, nb);
    pscan_kernel<<<nb, 256, 0, stream>>>(cnt, Nn, bsum, ptr);
    bscan2_kernel<<<1, 512, 0, stream>>>(bcnt, boff, nbk);
    bucket_scatter<<<(E + 255) / 256, 256, 0, stream>>>(ei, E, boff, btail, ebuf);
    {
        dim3 g(nbk, 8);
        csr_fill<<<g, 256, 0, stream>>>(ebuf, boff, ptr, fillb, adj);
    }
    padfill_kernel<<<(Nn + 255) / 256, 256, 0, stream>>>(cnt, ptr, adj, Nn);
    zdum_kernel<<<1, 128, 0, stream>>>(sA, sB, Nn);

    // ---- GEMM2 (writes s0 bf16 + hidden fp32; needs dis) ----
    mfma_gemm2<<<(Nn + 127) / 128, 256, 0, stream>>>(hmid, W2T, b2, sA, hidden, temp, dis, Nn);

    // ---- K-hop propagation ----
    int pg = (Nn + 3) / 4;
    for (int k = 0; k < KHOP; k++) {
        const unsigned short* sin = (k & 1) ? sB : sA;
        unsigned short*       so  = (k & 1) ? sA : sB;
        prop_kernel<<<pg, 256, 0, stream>>>(sin, so, hidden, ptr, adj, dis, temp, k, Nn);
    }

    // ---- log-softmax ----
    lsm_kernel<<<pg, 256, 0, stream>>>(hidden, (float*)d_out, Nn);
}